// Round 15
// baseline (148.620 us; speedup 1.0000x reference)
//
#include <hip/hip_runtime.h>
#include <hip/hip_fp16.h>

#define NN 8192
#define DIN 7
#define DH 8
#define DOUT 23
#define CUTOFF 3.6f
#define SLOPE 0.01f

#define JC 512               // j-chunk per k3 block (16 atomic chunks/row: benign level)
#define ROWS 128             // rows per k3 block (4 waves x 2 tiles x 16) — R12 optimum
#define PPITCH 520           // padded row pitch (shorts) for P in LDS
#define NJS (JC / 32)        // 16 K-steps of 32

typedef float  v4f __attribute__((ext_vector_type(4)));
typedef short  v8s __attribute__((ext_vector_type(8)));
typedef unsigned int v4u __attribute__((ext_vector_type(4)));

__device__ __forceinline__ float leaky(float v) { return v >= 0.0f ? v : SLOPE * v; }

// Per-node feature pipeline — computed ONCE per node in k_stage.
__device__ __forceinline__ void node_feats(
    const float* __restrict__ x,
    const float* __restrict__ W1, const float* __restrict__ b1,
    const float* __restrict__ W2, const float* __restrict__ b2,
    const float* __restrict__ W3, const float* __restrict__ b3,
    int n, float coord[3], float& E, float ev[7])
{
    float xi[DIN];
#pragma unroll
    for (int d = 0; d < DIN; ++d) xi[d] = x[n * DIN + d];
    coord[0] = xi[0]; coord[1] = xi[1]; coord[2] = xi[2];

    float h1[DH];
#pragma unroll
    for (int k = 0; k < DH; ++k) {
        float t = b1[k];
#pragma unroll
        for (int d = 0; d < DIN; ++d) t = fmaf(W1[k * DIN + d], xi[d], t);
        h1[k] = leaky(t);
    }
    float h2[DH];
#pragma unroll
    for (int k = 0; k < DH; ++k) {
        float t = b2[k];
#pragma unroll
        for (int d = 0; d < DH; ++d) t = fmaf(W2[k * DH + d], h1[d], t);
        h2[k] = leaky(t);
    }
    float h3[DOUT];
#pragma unroll
    for (int m = 0; m < DOUT; ++m) {
        float t = b3[m];
#pragma unroll
        for (int d = 0; d < DH; ++d) t = fmaf(W3[m * DH + d], h2[d], t);
        h3[m] = t;
    }
    float s = 0.0f;
#pragma unroll
    for (int k = 0; k < 8; ++k) s = fmaf(h3[7 + k], h3[15 + k], s);
    // |s| ~ O(1) -> exp without max-shift safe in fp32; softmax ratio shift-invariant.
    E = expf(s);
#pragma unroll
    for (int q = 0; q < 7; ++q) ev[q] = h3[q] * E;
}

// ---------------- K_stage: once-per-node features -> global; zero accum + done ----------
__global__ __launch_bounds__(256) void k_stage(
    const float* __restrict__ x,
    const float* __restrict__ W1, const float* __restrict__ b1,
    const float* __restrict__ W2, const float* __restrict__ b2,
    const float* __restrict__ W3, const float* __restrict__ b3,
    unsigned short* __restrict__ gX16, unsigned short* __restrict__ gY16,
    unsigned short* __restrict__ gZ16,
    short* __restrict__ gPhi,
    float* __restrict__ gEvE, float* __restrict__ accum,
    unsigned* __restrict__ done)
{
    int n = blockIdx.x * 256 + threadIdx.x;
    if (blockIdx.x == 0 && threadIdx.x < 64) done[threadIdx.x] = 0u;  // ws is poisoned
    float c[3], E, ev[7];
    node_feats(x, W1, b1, W2, b2, W3, b3, n, c, E, ev);
    gX16[n] = __builtin_bit_cast(unsigned short, __float2half(c[0]));
    gY16[n] = __builtin_bit_cast(unsigned short, __float2half(c[1]));
    gZ16[n] = __builtin_bit_cast(unsigned short, __float2half(c[2]));
    float pv[8] = {ev[0], ev[1], ev[2], ev[3], ev[4], ev[5], ev[6], E};
#pragma unroll
    for (int q = 0; q < 8; ++q) {
        unsigned u = __float_as_uint(pv[q]);
        unsigned h = (u + 0x7FFFu + ((u >> 16) & 1u)) >> 16;   // RTNE to bf16
        gPhi[q * NN + n] = (short)h;
        gEvE[n * 8 + q] = __uint_as_float(h << 16);            // the rounded value
        accum[q * NN + n] = 0.0f;
    }
}

// ---------------- K3: mask x P via bf16 MFMA (R12 config) + fused last-block finalize ----
// grid (64, 16): 1024 blocks = 4 blocks/CU = 4 waves/SIMD; 16 atomic chunks/row.
// After accumulation, the 16th-arriving block per row-group runs the k4 epilogue inline
// (decoupled last-block pattern: release fence -> counter -> acquire + agent-scope loads).
__global__ __launch_bounds__(256, 4) void k3_mfma(
    const unsigned short* __restrict__ gX16, const unsigned short* __restrict__ gY16,
    const unsigned short* __restrict__ gZ16,
    const short* __restrict__ gPhi,
    float* __restrict__ accum,
    const float* __restrict__ x,
    const float* __restrict__ We, const float* __restrict__ be,
    const float* __restrict__ Wd, const float* __restrict__ bd,
    const float* __restrict__ gEvE,
    unsigned* __restrict__ done,
    float* __restrict__ out)
{
    __shared__ __attribute__((aligned(16))) unsigned short sX16[JC];
    __shared__ __attribute__((aligned(16))) unsigned short sY16[JC];
    __shared__ __attribute__((aligned(16))) unsigned short sZ16[JC];
    __shared__ __attribute__((aligned(16))) short sPhi[8 * PPITCH];

    int tid = threadIdx.x;
    int jBase = blockIdx.y * JC;
    int rowBase = blockIdx.x * ROWS;

    // LDS fill: 256 dwords per coord axis; P rows rotated by 4 dwords/q (bank swizzle)
    ((unsigned*)sX16)[tid] = ((const unsigned*)(gX16 + jBase))[tid];
    ((unsigned*)sY16)[tid] = ((const unsigned*)(gY16 + jBase))[tid];
    ((unsigned*)sZ16)[tid] = ((const unsigned*)(gZ16 + jBase))[tid];
#pragma unroll
    for (int q = 0; q < 8; ++q) {
        const unsigned* sh = (const unsigned*)(gPhi + (size_t)q * NN + jBase);
        ((unsigned*)(sPhi + q * PPITCH))[(tid + 4 * q) & 255] = sh[tid];
    }

    int wave = tid >> 6;
    int lane = tid & 63;
    int lm = lane & 15;      // A-row within tile / C-col (q)
    int q4 = lane >> 4;      // k-slice quad
    int bcol = lm & 7;       // B-row; cols 8-15 mirror 0-7 (never stored)

    // row coords for this lane's 2 tiles, broadcast-packed {h,h}
    __half2 rx2[2], ry2[2], rz2[2];
#pragma unroll
    for (int t = 0; t < 2; ++t) {
        int r = rowBase + wave * 32 + t * 16 + lm;
        unsigned hx = gX16[r], hy = gY16[r], hz = gZ16[r];
        rx2[t] = __builtin_bit_cast(__half2, (unsigned)(hx | (hx << 16)));
        ry2[t] = __builtin_bit_cast(__half2, (unsigned)(hy | (hy << 16)));
        rz2[t] = __builtin_bit_cast(__half2, (unsigned)(hz | (hz << 16)));
    }
    const __half2 C2 = __floats2half2_rn(CUTOFF, CUTOFF);

    v4f c0 = {0.f, 0.f, 0.f, 0.f};
    v4f c1 = {0.f, 0.f, 0.f, 0.f};

    __syncthreads();

#define LOADF(JS, BH, UX, UY, UZ) do {                                       \
        int jb_ = (JS) * 32 + q4 * 8;                                        \
        int jr_ = (jb_ + 8 * bcol) & (JC - 1);                               \
        BH = *(const v8s*)&sPhi[bcol * PPITCH + jr_];                        \
        UX = *(const v4u*)&sX16[jb_];                                        \
        UY = *(const v4u*)&sY16[jb_];                                        \
        UZ = *(const v4u*)&sZ16[jb_];                                        \
    } while (0)

#define COMPUTEF(BH, UX, UY, UZ) do {                                        \
        _Pragma("unroll")                                                    \
        for (int t = 0; t < 2; ++t) {                                        \
            v4u pk;                                                          \
            _Pragma("unroll")                                                \
            for (int i2 = 0; i2 < 4; ++i2) {                                 \
                __half2 jx2 = __builtin_bit_cast(__half2, UX[i2]);           \
                __half2 jy2 = __builtin_bit_cast(__half2, UY[i2]);           \
                __half2 jz2 = __builtin_bit_cast(__half2, UZ[i2]);           \
                __half2 da = __habs2(__hsub2(rx2[t], jx2));                  \
                __half2 db = __habs2(__hsub2(ry2[t], jy2));                  \
                __half2 dc = __habs2(__hsub2(rz2[t], jz2));                  \
                __half2 d2 = __hadd2(__hadd2(da, db), dc);                   \
                __half2 m2 = __hsub2(C2, d2);  /* sign clear (incl 0) = adj */\
                unsigned um = __builtin_bit_cast(unsigned, m2);              \
                unsigned adj = ((um >> 15) & 0x00010001u) ^ 0x00010001u;     \
                pk[i2] = adj * 0x3F80u;       /* packs both bf16 1.0s */     \
            }                                                                \
            v8s a_ = __builtin_bit_cast(v8s, pk);                            \
            v4f* cp = (t == 0) ? &c0 : &c1;                                  \
            *cp = __builtin_amdgcn_mfma_f32_16x16x32_bf16(a_, BH, *cp, 0, 0, 0); \
        }                                                                    \
    } while (0)

    v8s bhiA, bhiB;
    v4u uxA, uyA, uzA, uxB, uyB, uzB;

    LOADF(0, bhiA, uxA, uyA, uzA);
#pragma unroll 1
    for (int js = 0; js < NJS; js += 2) {
        LOADF(js + 1, bhiB, uxB, uyB, uzB);
        COMPUTEF(bhiA, uxA, uyA, uzA);
        if (js + 2 < NJS) LOADF(js + 2, bhiA, uxA, uyA, uzA);
        COMPUTEF(bhiB, uxB, uyB, uzB);
    }

    // C layout: col=lane&15 (q), row=(lane>>4)*4+reg. Only cols 0..7 are real.
    if (lm < 8) {
        v4f cc[2] = {c0, c1};
#pragma unroll
        for (int t = 0; t < 2; ++t) {
            int rb = rowBase + wave * 32 + t * 16 + q4 * 4;
#pragma unroll
            for (int reg = 0; reg < 4; ++reg)
                atomicAdd(&accum[lm * NN + rb + reg], cc[t][reg]);
        }
    }
#undef LOADF
#undef COMPUTEF

    // ---- fused k4: the 16th-arriving block for this row-group finalizes its 128 rows ----
    __threadfence();                       // release: my accum atomics visible device-wide
    __shared__ unsigned sLast;
    if (tid == 0)
        sLast = (atomicAdd(&done[blockIdx.x], 1u) == 15u) ? 1u : 0u;
    __syncthreads();
    if (sLast && tid < ROWS) {
        __threadfence();                   // acquire
        int n = rowBase + tid;
        float a[8];
#pragma unroll
        for (int q = 0; q < 8; ++q)
            a[q] = __hip_atomic_load(&accum[q * NN + n], __ATOMIC_RELAXED,
                                     __HIP_MEMORY_SCOPE_AGENT);
        float4 e0 = *(const float4*)&gEvE[n * 8];
        float4 e1 = *(const float4*)&gEvE[n * 8 + 4];
        float ev[7] = {e0.x, e0.y, e0.z, e0.w, e1.x, e1.y, e1.z};
        float E = e1.w;

        float denom = fmaxf(a[7] - E, 1e-30f);   // remove diagonal (exact cancel)
        float inv = 1.0f / denom;

        float inp[14];
#pragma unroll
        for (int d = 0; d < DIN; ++d) inp[d] = x[n * DIN + d];
#pragma unroll
        for (int q = 0; q < 7; ++q) inp[7 + q] = (a[q] - ev[q]) * inv;

        float codes[DH];
#pragma unroll
        for (int k = 0; k < DH; ++k) {
            float t2 = be[k];
#pragma unroll
            for (int d = 0; d < 14; ++d) t2 = fmaf(We[k * 14 + d], inp[d], t2);
            codes[k] = leaky(t2);
        }
#pragma unroll
        for (int cc2 = 0; cc2 < DIN; ++cc2) {
            float t2 = bd[cc2];
#pragma unroll
            for (int k = 0; k < DH; ++k) t2 = fmaf(Wd[cc2 * DH + k], codes[k], t2);
            out[(size_t)n * DIN + cc2] = t2;
        }
    }
}

extern "C" void kernel_launch(void* const* d_in, const int* in_sizes, int n_in,
                              void* d_out, int out_size, void* d_ws, size_t ws_size,
                              hipStream_t stream) {
    const float* x  = (const float*)d_in[0];
    const float* W1 = (const float*)d_in[1];
    const float* b1 = (const float*)d_in[2];
    const float* W2 = (const float*)d_in[3];
    const float* b2 = (const float*)d_in[4];
    const float* W3 = (const float*)d_in[5];
    const float* b3 = (const float*)d_in[6];
    const float* We = (const float*)d_in[7];
    const float* be = (const float*)d_in[8];
    const float* Wd = (const float*)d_in[9];
    const float* bd = (const float*)d_in[10];
    float* out = (float*)d_out;

    char* ws = (char*)d_ws;
    unsigned short* gX16 = (unsigned short*)ws;    ws += NN * 2;            // 16 KB
    unsigned short* gY16 = (unsigned short*)ws;    ws += NN * 2;
    unsigned short* gZ16 = (unsigned short*)ws;    ws += NN * 2;
    short* gPhi  = (short*)ws;                     ws += 8 * NN * 2;        // 128 KB
    float* gEvE  = (float*)ws;                     ws += 8 * NN * 4;        // 256 KB
    float* accum = (float*)ws;                     ws += 8 * NN * 4;        // 256 KB
    unsigned* done = (unsigned*)ws;                                        // 256 B

    k_stage<<<32, 256, 0, stream>>>(x, W1, b1, W2, b2, W3, b3,
                                    gX16, gY16, gZ16, gPhi, gEvE, accum, done);
    dim3 g3(NN / ROWS, NN / JC);  // (64, 16) = 1024 blocks
    k3_mfma<<<g3, 256, 0, stream>>>(gX16, gY16, gZ16, gPhi, accum,
                                    x, We, be, Wd, bd, gEvE, done, out);
}

// Round 16
// 101.598 us; speedup vs baseline: 1.4628x; 1.4628x over previous
//
#include <hip/hip_runtime.h>
#include <hip/hip_fp16.h>

#define NN 8192
#define DIN 7
#define DH 8
#define DOUT 23
#define CUTOFF 3.6f
#define SLOPE 0.01f

#define JC 512               // j-chunk per k3 block
#define ROWS 128             // rows per k3 block (4 waves x 2 tiles x 16)
#define PPITCH 520           // padded row pitch (shorts) for P in LDS
#define NJS (JC / 32)        // 16 K-steps of 32

typedef float  v4f __attribute__((ext_vector_type(4)));
typedef short  v8s __attribute__((ext_vector_type(8)));
typedef unsigned int v4u __attribute__((ext_vector_type(4)));

__device__ __forceinline__ float leaky(float v) { return v >= 0.0f ? v : SLOPE * v; }

// Per-node feature pipeline — computed ONCE per node in k_stage.
__device__ __forceinline__ void node_feats(
    const float* __restrict__ x,
    const float* __restrict__ W1, const float* __restrict__ b1,
    const float* __restrict__ W2, const float* __restrict__ b2,
    const float* __restrict__ W3, const float* __restrict__ b3,
    int n, float coord[3], float& E, float ev[7])
{
    float xi[DIN];
#pragma unroll
    for (int d = 0; d < DIN; ++d) xi[d] = x[n * DIN + d];
    coord[0] = xi[0]; coord[1] = xi[1]; coord[2] = xi[2];

    float h1[DH];
#pragma unroll
    for (int k = 0; k < DH; ++k) {
        float t = b1[k];
#pragma unroll
        for (int d = 0; d < DIN; ++d) t = fmaf(W1[k * DIN + d], xi[d], t);
        h1[k] = leaky(t);
    }
    float h2[DH];
#pragma unroll
    for (int k = 0; k < DH; ++k) {
        float t = b2[k];
#pragma unroll
        for (int d = 0; d < DH; ++d) t = fmaf(W2[k * DH + d], h1[d], t);
        h2[k] = leaky(t);
    }
    float h3[DOUT];
#pragma unroll
    for (int m = 0; m < DOUT; ++m) {
        float t = b3[m];
#pragma unroll
        for (int d = 0; d < DH; ++d) t = fmaf(W3[m * DH + d], h2[d], t);
        h3[m] = t;
    }
    float s = 0.0f;
#pragma unroll
    for (int k = 0; k < 8; ++k) s = fmaf(h3[7 + k], h3[15 + k], s);
    // |s| ~ O(1) -> exp without max-shift safe in fp32; softmax ratio shift-invariant.
    E = expf(s);
#pragma unroll
    for (int q = 0; q < 7; ++q) ev[q] = h3[q] * E;
}

// ---------------- K_stage: once-per-node features -> global; zero accum ------------------
// Coords stored as f16 (packed-f16 mask path; ~0.2% borderline flips, within threshold).
// P rounded to bf16 RTNE; gEvE stores the SAME rounded values as fp32 so k4's diagonal
// subtraction cancels exactly against what the MFMA accumulated.
__global__ __launch_bounds__(256) void k_stage(
    const float* __restrict__ x,
    const float* __restrict__ W1, const float* __restrict__ b1,
    const float* __restrict__ W2, const float* __restrict__ b2,
    const float* __restrict__ W3, const float* __restrict__ b3,
    unsigned short* __restrict__ gX16, unsigned short* __restrict__ gY16,
    unsigned short* __restrict__ gZ16,
    short* __restrict__ gPhi,
    float* __restrict__ gEvE, float* __restrict__ accum)
{
    int n = blockIdx.x * 256 + threadIdx.x;
    float c[3], E, ev[7];
    node_feats(x, W1, b1, W2, b2, W3, b3, n, c, E, ev);
    gX16[n] = __builtin_bit_cast(unsigned short, __float2half(c[0]));
    gY16[n] = __builtin_bit_cast(unsigned short, __float2half(c[1]));
    gZ16[n] = __builtin_bit_cast(unsigned short, __float2half(c[2]));
    float pv[8] = {ev[0], ev[1], ev[2], ev[3], ev[4], ev[5], ev[6], E};
#pragma unroll
    for (int q = 0; q < 8; ++q) {
        unsigned u = __float_as_uint(pv[q]);
        unsigned h = (u + 0x7FFFu + ((u >> 16) & 1u)) >> 16;   // RTNE to bf16
        gPhi[q * NN + n] = (short)h;
        gEvE[n * 8 + q] = __uint_as_float(h << 16);            // the rounded value
        accum[q * NN + n] = 0.0f;
    }
}

// ---------------- K3: C = mask x P via bf16 MFMA; packed-f16 mask datapath ---------------
// grid (64, 16): 1024 blocks = 4 blocks/CU = 4 waves/SIMD. 16 atomic chunks/row (benign;
// 32 chunks cost +18us — measured R4 & R13). Per K-step: 3 coord ds_read_b128 (f16) +
// 1 P read; masks for 2 j per packed-f16 chain, adjacency bits from sign bits (no VCC).
__global__ __launch_bounds__(256, 4) void k3_mfma(
    const unsigned short* __restrict__ gX16, const unsigned short* __restrict__ gY16,
    const unsigned short* __restrict__ gZ16,
    const short* __restrict__ gPhi,
    float* __restrict__ accum)
{
    __shared__ __attribute__((aligned(16))) unsigned short sX16[JC];
    __shared__ __attribute__((aligned(16))) unsigned short sY16[JC];
    __shared__ __attribute__((aligned(16))) unsigned short sZ16[JC];
    __shared__ __attribute__((aligned(16))) short sPhi[8 * PPITCH];

    int tid = threadIdx.x;
    int jBase = blockIdx.y * JC;
    int rowBase = blockIdx.x * ROWS;

    // LDS fill: coords as packed halves (256 dwords per axis), P rows rotated (bank swizzle)
    ((unsigned*)sX16)[tid] = ((const unsigned*)(gX16 + jBase))[tid];
    ((unsigned*)sY16)[tid] = ((const unsigned*)(gY16 + jBase))[tid];
    ((unsigned*)sZ16)[tid] = ((const unsigned*)(gZ16 + jBase))[tid];
#pragma unroll
    for (int q = 0; q < 8; ++q) {
        const unsigned* sh = (const unsigned*)(gPhi + (size_t)q * NN + jBase);
        ((unsigned*)(sPhi + q * PPITCH))[(tid + 4 * q) & 255] = sh[tid];
    }

    int wave = tid >> 6;
    int lane = tid & 63;
    int lm = lane & 15;      // A-row within tile / C-col (q)
    int q4 = lane >> 4;      // k-slice quad
    int bcol = lm & 7;       // B-row; cols 8-15 mirror 0-7 (never stored)

    // row coords for this lane's 2 tiles, broadcast-packed {h,h}
    __half2 rx2[2], ry2[2], rz2[2];
#pragma unroll
    for (int t = 0; t < 2; ++t) {
        int r = rowBase + wave * 32 + t * 16 + lm;
        unsigned hx = gX16[r], hy = gY16[r], hz = gZ16[r];
        rx2[t] = __builtin_bit_cast(__half2, (unsigned)(hx | (hx << 16)));
        ry2[t] = __builtin_bit_cast(__half2, (unsigned)(hy | (hy << 16)));
        rz2[t] = __builtin_bit_cast(__half2, (unsigned)(hz | (hz << 16)));
    }
    const __half2 C2 = __floats2half2_rn(CUTOFF, CUTOFF);

    v4f c0 = {0.f, 0.f, 0.f, 0.f};
    v4f c1 = {0.f, 0.f, 0.f, 0.f};

    __syncthreads();

#define LOADF(JS, BH, UX, UY, UZ) do {                                       \
        int jb_ = (JS) * 32 + q4 * 8;                                        \
        int jr_ = (jb_ + 8 * bcol) & (JC - 1);                               \
        BH = *(const v8s*)&sPhi[bcol * PPITCH + jr_];                        \
        UX = *(const v4u*)&sX16[jb_];                                        \
        UY = *(const v4u*)&sY16[jb_];                                        \
        UZ = *(const v4u*)&sZ16[jb_];                                        \
    } while (0)

#define COMPUTEF(BH, UX, UY, UZ) do {                                        \
        _Pragma("unroll")                                                    \
        for (int t = 0; t < 2; ++t) {                                        \
            v4u pk;                                                          \
            _Pragma("unroll")                                                \
            for (int i2 = 0; i2 < 4; ++i2) {                                 \
                __half2 jx2 = __builtin_bit_cast(__half2, UX[i2]);           \
                __half2 jy2 = __builtin_bit_cast(__half2, UY[i2]);           \
                __half2 jz2 = __builtin_bit_cast(__half2, UZ[i2]);           \
                __half2 da = __habs2(__hsub2(rx2[t], jx2));                  \
                __half2 db = __habs2(__hsub2(ry2[t], jy2));                  \
                __half2 dc = __habs2(__hsub2(rz2[t], jz2));                  \
                __half2 d2 = __hadd2(__hadd2(da, db), dc);                   \
                __half2 m2 = __hsub2(C2, d2);  /* sign clear (incl 0) = adj */\
                unsigned um = __builtin_bit_cast(unsigned, m2);              \
                unsigned adj = ((um >> 15) & 0x00010001u) ^ 0x00010001u;     \
                pk[i2] = adj * 0x3F80u;       /* packs both bf16 1.0s */     \
            }                                                                \
            v8s a_ = __builtin_bit_cast(v8s, pk);                            \
            v4f* cp = (t == 0) ? &c0 : &c1;                                  \
            *cp = __builtin_amdgcn_mfma_f32_16x16x32_bf16(a_, BH, *cp, 0, 0, 0); \
        }                                                                    \
    } while (0)

    v8s bhiA, bhiB;
    v4u uxA, uyA, uzA, uxB, uyB, uzB;

    LOADF(0, bhiA, uxA, uyA, uzA);
#pragma unroll 1
    for (int js = 0; js < NJS; js += 2) {
        LOADF(js + 1, bhiB, uxB, uyB, uzB);
        COMPUTEF(bhiA, uxA, uyA, uzA);
        if (js + 2 < NJS) LOADF(js + 2, bhiA, uxA, uyA, uzA);
        COMPUTEF(bhiB, uxB, uyB, uzB);
    }

    // C layout: col=lane&15 (q), row=(lane>>4)*4+reg. Only cols 0..7 are real.
    if (lm < 8) {
        v4f cc[2] = {c0, c1};
#pragma unroll
        for (int t = 0; t < 2; ++t) {
            int rb = rowBase + wave * 32 + t * 16 + q4 * 4;
#pragma unroll
            for (int reg = 0; reg < 4; ++reg)
                atomicAdd(&accum[lm * NN + rb + reg], cc[t][reg]);
        }
    }
#undef LOADF
#undef COMPUTEF
}

// ---------------- K4: finalize from staged rounded E/ev (exact cancel), MLP, store -------
__global__ __launch_bounds__(256) void k4_final(
    const float* __restrict__ x,
    const float* __restrict__ We, const float* __restrict__ be,
    const float* __restrict__ Wd, const float* __restrict__ bd,
    const float* __restrict__ gEvE,
    const float* __restrict__ accum, float* __restrict__ out)
{
    int n = blockIdx.x * 256 + threadIdx.x;

    float4 e0 = *(const float4*)&gEvE[n * 8];
    float4 e1 = *(const float4*)&gEvE[n * 8 + 4];
    float ev[7] = {e0.x, e0.y, e0.z, e0.w, e1.x, e1.y, e1.z};
    float E = e1.w;

    float denom = accum[7 * NN + n] - E;   // remove diagonal (always within cutoff)
    denom = fmaxf(denom, 1e-30f);
    float inv = 1.0f / denom;

    float inp[14];
#pragma unroll
    for (int d = 0; d < DIN; ++d) inp[d] = x[n * DIN + d];
#pragma unroll
    for (int q = 0; q < 7; ++q) inp[7 + q] = (accum[q * NN + n] - ev[q]) * inv;

    float codes[DH];
#pragma unroll
    for (int k = 0; k < DH; ++k) {
        float t = be[k];
#pragma unroll
        for (int d = 0; d < 14; ++d) t = fmaf(We[k * 14 + d], inp[d], t);
        codes[k] = leaky(t);
    }
#pragma unroll
    for (int cc = 0; cc < DIN; ++cc) {
        float t = bd[cc];
#pragma unroll
        for (int k = 0; k < DH; ++k) t = fmaf(Wd[cc * DH + k], codes[k], t);
        out[(size_t)n * DIN + cc] = t;
    }
}

extern "C" void kernel_launch(void* const* d_in, const int* in_sizes, int n_in,
                              void* d_out, int out_size, void* d_ws, size_t ws_size,
                              hipStream_t stream) {
    const float* x  = (const float*)d_in[0];
    const float* W1 = (const float*)d_in[1];
    const float* b1 = (const float*)d_in[2];
    const float* W2 = (const float*)d_in[3];
    const float* b2 = (const float*)d_in[4];
    const float* W3 = (const float*)d_in[5];
    const float* b3 = (const float*)d_in[6];
    const float* We = (const float*)d_in[7];
    const float* be = (const float*)d_in[8];
    const float* Wd = (const float*)d_in[9];
    const float* bd = (const float*)d_in[10];
    float* out = (float*)d_out;

    char* ws = (char*)d_ws;
    unsigned short* gX16 = (unsigned short*)ws;    ws += NN * 2;            // 16 KB
    unsigned short* gY16 = (unsigned short*)ws;    ws += NN * 2;
    unsigned short* gZ16 = (unsigned short*)ws;    ws += NN * 2;
    short* gPhi  = (short*)ws;                     ws += 8 * NN * 2;        // 128 KB
    float* gEvE  = (float*)ws;                     ws += 8 * NN * 4;        // 256 KB
    float* accum = (float*)ws;                                             // 256 KB

    k_stage<<<32, 256, 0, stream>>>(x, W1, b1, W2, b2, W3, b3,
                                    gX16, gY16, gZ16, gPhi, gEvE, accum);
    dim3 g3(NN / ROWS, NN / JC);  // (64, 16) = 1024 blocks
    k3_mfma<<<g3, 256, 0, stream>>>(gX16, gY16, gZ16, gPhi, accum);
    k4_final<<<32, 256, 0, stream>>>(x, We, be, Wd, bd, gEvE, accum, out);
}